// Round 1
// 383.153 us; speedup vs baseline: 1.0588x; 1.0588x over previous
//
#include <hip/hip_runtime.h>
#include <hip/hip_bf16.h>

typedef unsigned short u16;
typedef __attribute__((ext_vector_type(8))) short short8;
typedef __attribute__((ext_vector_type(4))) float f32x4;

#define B_ 8
#define V_ 64
#define T_ 256
#define T1_ 257
#define D_ 256
#define H_ 8
#define DH_ 32

__device__ __forceinline__ u16 f2bf(float f){
  union { float f; unsigned int u; } v; v.f = f;
  unsigned int u = v.u;
  return (u16)((u + 0x7fffu + ((u >> 16) & 1u)) >> 16);
}

// ---------------- kernel 0: weights -> bf16, + zero xsum ----------------
__global__ void k0_conv(const float* __restrict__ wqkv, const float* __restrict__ wproj,
                        u16* __restrict__ wv, u16* __restrict__ wp, float* __restrict__ xsum){
  int i = blockIdx.x * 256 + threadIdx.x;   // 512 blocks -> 131072
  if (i < 65536) wv[i] = f2bf(wqkv[131072 + i]);     // rows 512..767 = Wv
  else           wp[i - 65536] = f2bf(wproj[i - 65536]);
  xsum[i] = 0.f;
}

// ---------------- kernel 1: LN stats + masked xn-sum ----------------
// grid (B*V, 4), block 256 = 4 waves. Each HALF-WAVE owns one t (8 floats/lane,
// 5-level butterfly within 32 lanes). Wave processes a PAIR of t's per iter ->
// half the shuffle work per byte vs one-t-per-wave.
__global__ void k1_ln(const float* __restrict__ x, const int* __restrict__ mask,
                      const float* __restrict__ lnw, const float* __restrict__ lnb,
                      float* __restrict__ musig, float* __restrict__ xsum){
  int bv = blockIdx.x;
  int tid = threadIdx.x;
  int lane = tid & 63, wid = tid >> 6;
  int half = lane >> 5, l32 = lane & 31;
  int c8 = l32 * 8;
  __shared__ float xsred[4][512];
  float4 w0 = *(const float4*)&lnw[c8], w1 = *(const float4*)&lnw[c8 + 4];
  float4 b0 = *(const float4*)&lnb[c8], b1 = *(const float4*)&lnb[c8 + 4];
  float xs[8];
  #pragma unroll
  for (int j = 0; j < 8; ++j) xs[j] = 0.f;
  for (int p = blockIdx.y * 4 + wid; p < 129; p += 16){
    int t = p * 2 + half;
    bool valid = (t < T1_);
    float4 a0 = {0.f,0.f,0.f,0.f}, a1 = {0.f,0.f,0.f,0.f};
    if (valid){
      const float* gp = &x[((long)bv * T1_ + t) * D_ + c8];
      a0 = *(const float4*)gp; a1 = *(const float4*)(gp + 4);
    }
    float s  = a0.x + a0.y + a0.z + a0.w + a1.x + a1.y + a1.z + a1.w;
    float s2 = a0.x*a0.x + a0.y*a0.y + a0.z*a0.z + a0.w*a0.w
             + a1.x*a1.x + a1.y*a1.y + a1.z*a1.z + a1.w*a1.w;
    #pragma unroll
    for (int off = 1; off < 32; off <<= 1){
      s  += __shfl_xor(s,  off, 64);
      s2 += __shfl_xor(s2, off, 64);
    }
    float mu   = s * (1.f / 256.f);
    float var  = s2 * (1.f / 256.f) - mu * mu;
    float rstd = rsqrtf(var + 1e-5f);
    if (valid){
      if (l32 == 0){
        musig[((long)bv * T1_ + t) * 2]     = mu;
        musig[((long)bv * T1_ + t) * 2 + 1] = rstd;
      }
      int m = (t == 0) ? 1 : mask[bv * T_ + (t - 1)];
      if (m){
        xs[0] += (a0.x - mu) * rstd * w0.x + b0.x;
        xs[1] += (a0.y - mu) * rstd * w0.y + b0.y;
        xs[2] += (a0.z - mu) * rstd * w0.z + b0.z;
        xs[3] += (a0.w - mu) * rstd * w0.w + b0.w;
        xs[4] += (a1.x - mu) * rstd * w1.x + b1.x;
        xs[5] += (a1.y - mu) * rstd * w1.y + b1.y;
        xs[6] += (a1.z - mu) * rstd * w1.z + b1.z;
        xs[7] += (a1.w - mu) * rstd * w1.w + b1.w;
      }
    }
  }
  #pragma unroll
  for (int j = 0; j < 8; ++j) xsred[wid][half * 256 + c8 + j] = xs[j];
  __syncthreads();
  float r = 0.f;
  #pragma unroll
  for (int w2 = 0; w2 < 4; ++w2) r += xsred[w2][tid] + xsred[w2][256 + tid];
  atomicAdd(&xsum[bv * D_ + tid], r);
}

// ---------------- kernel 2a: q,k projections (tiny) ----------------
__global__ void k2a_qk(const float* __restrict__ x, const int* __restrict__ mask,
                       const float* __restrict__ lnw, const float* __restrict__ lnb,
                       const float* __restrict__ wqkv,
                       const float* __restrict__ musig, const float* __restrict__ xsum,
                       float* __restrict__ qout, float* __restrict__ kout){
  int bv = blockIdx.x, tid = threadIdx.x;
  int lane = tid & 63, wid = tid >> 6;
  __shared__ __align__(16) float xn0[D_];
  __shared__ __align__(16) float xs[D_];
  __shared__ float redc[4];
  int s = mask[bv * T_ + tid];
  #pragma unroll
  for (int off = 32; off >= 1; off >>= 1) s += __shfl_down(s, off, 64);
  if (lane == 0) redc[wid] = (float)s;
  __syncthreads();
  float cnt = 1.f + redc[0] + redc[1] + redc[2] + redc[3];
  float mu = musig[((long)bv * T1_) * 2], rstd = musig[((long)bv * T1_) * 2 + 1];
  xn0[tid] = (x[((long)bv * T1_) * D_ + tid] - mu) * rstd * lnw[tid] + lnb[tid];
  xs[tid]  = xsum[bv * D_ + tid] * (1.f / cnt);
  __syncthreads();
  float4 xq = *(const float4*)&xn0[lane * 4];
  float4 xk = *(const float4*)&xs[lane * 4];
  int e0 = (blockIdx.y * 4 + wid) * 16;
  for (int i = 0; i < 16; ++i){
    int e = e0 + i;
    float4 wq4 = *(const float4*)&wqkv[(long)e * D_ + lane * 4];
    float4 wk4 = *(const float4*)&wqkv[(long)(256 + e) * D_ + lane * 4];
    float sq = xq.x*wq4.x + xq.y*wq4.y + xq.z*wq4.z + xq.w*wq4.w;
    float sk = xk.x*wk4.x + xk.y*wk4.y + xk.z*wk4.z + xk.w*wk4.w;
    #pragma unroll
    for (int off = 32; off >= 1; off >>= 1){
      sq += __shfl_down(sq, off, 64);
      sk += __shfl_down(sk, off, 64);
    }
    if (lane == 0){ qout[bv * D_ + e] = sq; kout[bv * D_ + e] = sk; }
  }
}

// ---------------- kernel 2b: 64x64 attention per (b,h) ----------------
// 256 threads: lane = key index, wave handles 16 q rows. Butterfly softmax
// across 64 lanes; padded LDS (stride 33 -> 2-way = free).
__global__ void k2b_attn(const float* __restrict__ q, const float* __restrict__ k,
                         u16* __restrict__ attn){
  int bh = blockIdx.x; int b = bh >> 3, h = bh & 7;
  int tid = threadIdx.x;
  int lane = tid & 63, wid = tid >> 6;
  __shared__ float qs[64][33], ks[64][33];
  #pragma unroll
  for (int j = 0; j < 2; ++j){
    int i4 = tid * 2 + j;
    int r = i4 >> 3, c4 = (i4 & 7) * 4;
    float4 vq = *(const float4*)&q[((long)(b * V_ + r)) * D_ + h * DH_ + c4];
    float4 vk = *(const float4*)&k[((long)(b * V_ + r)) * D_ + h * DH_ + c4];
    qs[r][c4] = vq.x; qs[r][c4+1] = vq.y; qs[r][c4+2] = vq.z; qs[r][c4+3] = vq.w;
    ks[r][c4] = vk.x; ks[r][c4+1] = vk.y; ks[r][c4+2] = vk.z; ks[r][c4+3] = vk.w;
  }
  __syncthreads();
  const float scale = 0.17677669529663687f;  // 1/sqrt(32)
  for (int i = 0; i < 16; ++i){
    int qr = i * 4 + wid;
    float a = 0.f;
    #pragma unroll
    for (int d = 0; d < DH_; ++d) a += qs[qr][d] * ks[lane][d];
    a *= scale;
    float mx = a;
    #pragma unroll
    for (int off = 1; off < 64; off <<= 1) mx = fmaxf(mx, __shfl_xor(mx, off, 64));
    float e = __expf(a - mx);
    float sum = e;
    #pragma unroll
    for (int off = 1; off < 64; off <<= 1) sum += __shfl_xor(sum, off, 64);
    attn[((long)bh * 64 + qr) * 64 + lane] = f2bf(e * (1.f / sum));
  }
}

// ---------------- kernel 3: fused LN -> V-proj -> attn-mix -> out-proj -> residual ----------------
// Same structure/LDS as before, but all global/L2 B-operands (wv, attn, wp) and
// the x slice are prefetched into registers with static indexing so the MFMA
// loops never stall on L2 latency. Target <=128 VGPR (launch_bounds 512,4).
__global__ __launch_bounds__(512, 4) void k3_main(
    const float* __restrict__ x, const float* __restrict__ lnw, const float* __restrict__ lnb,
    const float* __restrict__ bproj, const float* __restrict__ musig,
    const u16* __restrict__ wv, const u16* __restrict__ wp,
    const u16* __restrict__ attn, float* __restrict__ out){
  constexpr int XS = 264;   // row stride (bf16 elems) for Xs/Ms
  constexpr int VS = 72;    // row stride for transposed vf
  __shared__ __align__(16) u16 Xs[64 * XS];    // xn slice; reused as mix (Ms)
  __shared__ __align__(16) u16 VT[D_ * VS];    // vf transposed: [col][var]
  __shared__ float lnw_s[D_], lnb_s[D_], bp_s[D_];
  __shared__ float ms_s[V_ * 2];

  int bt = blockIdx.x; int b = bt / T1_, t = bt % T1_;
  int tid = threadIdx.x;
  int w = tid >> 6, lane = tid & 63, lm = lane & 15, lq = lane >> 4;
  int cw = w * 32;   // this wave's output-column base
  int h = w;

  // ---- prefetch Wv fragments for GEMM1 (16 x short8 = 64 VGPR) ----
  short8 wvf[16];
  #pragma unroll
  for (int kk = 0; kk < 8; ++kk)
    #pragma unroll
    for (int nt = 0; nt < 2; ++nt)
      wvf[kk*2+nt] = *(const short8*)&wv[(long)(cw + nt*16 + lm) * D_ + kk*32 + lq*8];

  // ---- prefetch x slice (8 x float4 = 32 VGPR) ----
  float4 xa[8];
  #pragma unroll
  for (int i = 0; i < 4; ++i){
    int seg = i * 512 + tid;          // 2048 segments of 8 elems
    int vr = seg >> 5;
    int c8 = (seg & 31) * 8;
    const float* gp = x + (((long)b * V_ + vr) * T1_ + t) * D_ + c8;
    xa[i*2]   = *(const float4*)gp;
    xa[i*2+1] = *(const float4*)(gp + 4);
  }

  if (tid < 256){ lnw_s[tid] = lnw[tid]; lnb_s[tid] = lnb[tid]; bp_s[tid] = bproj[tid]; }
  else if (tid < 384){
    int i = tid - 256;
    ms_s[i] = musig[(((long)b * V_ + (i >> 1)) * T1_ + t) * 2 + (i & 1)];
  }
  __syncthreads();

  // ---- stage x slice with LN applied, as bf16, into Xs ----
  #pragma unroll
  for (int i = 0; i < 4; ++i){
    int seg = i * 512 + tid;
    int vr = seg >> 5;
    int c8 = (seg & 31) * 8;
    float mu = ms_s[vr * 2], rs = ms_s[vr * 2 + 1];
    float av[8] = {xa[i*2].x, xa[i*2].y, xa[i*2].z, xa[i*2].w,
                   xa[i*2+1].x, xa[i*2+1].y, xa[i*2+1].z, xa[i*2+1].w};
    union { u16 us[8]; uint4 q4; } pk;
    #pragma unroll
    for (int j = 0; j < 8; ++j)
      pk.us[j] = f2bf((av[j] - mu) * rs * lnw_s[c8 + j] + lnb_s[c8 + j]);
    *(uint4*)&Xs[vr * XS + c8] = pk.q4;
  }
  __syncthreads();

  // ---- GEMM1: vf = Xs(64x256) @ Wv^T ; weights already in registers ----
  f32x4 acc1[4][2];
  #pragma unroll
  for (int mt = 0; mt < 4; ++mt)
    #pragma unroll
    for (int nt = 0; nt < 2; ++nt) acc1[mt][nt] = (f32x4){0.f, 0.f, 0.f, 0.f};
  #pragma unroll
  for (int kk = 0; kk < 8; ++kk){
    short8 af[4];
    #pragma unroll
    for (int mt = 0; mt < 4; ++mt)
      af[mt] = *(const short8*)&Xs[(mt * 16 + lm) * XS + kk * 32 + lq * 8];
    #pragma unroll
    for (int mt = 0; mt < 4; ++mt)
      #pragma unroll
      for (int nt = 0; nt < 2; ++nt)
        acc1[mt][nt] = __builtin_amdgcn_mfma_f32_16x16x32_bf16(af[mt], wvf[kk*2+nt], acc1[mt][nt], 0, 0, 0);
  }
  // write vf transposed (bf16): VT[col][var]
  #pragma unroll
  for (int mt = 0; mt < 4; ++mt)
    #pragma unroll
    for (int nt = 0; nt < 2; ++nt){
      int col = cw + nt * 16 + lm;
      int row = mt * 16 + lq * 4;
      union { u16 us[4]; uint2 q2; } pv;
      #pragma unroll
      for (int r = 0; r < 4; ++r) pv.us[r] = f2bf(acc1[mt][nt][r]);
      *(uint2*)&VT[col * VS + row] = pv.q2;
    }

  // ---- prefetch attn fragments (32 VGPR) + Wp half0 (32 VGPR), hidden by barrier ----
  short8 atf[8];
  #pragma unroll
  for (int kk = 0; kk < 2; ++kk)
    #pragma unroll
    for (int mt = 0; mt < 4; ++mt)
      atf[kk*4+mt] = *(const short8*)&attn[((long)(b * H_ + h) * 64 + mt * 16 + lm) * 64 + kk * 32 + lq * 8];
  short8 wpf0[8];
  #pragma unroll
  for (int kk = 0; kk < 4; ++kk)
    #pragma unroll
    for (int nt = 0; nt < 2; ++nt)
      wpf0[kk*2+nt] = *(const short8*)&wp[(long)(cw + nt*16 + lm) * D_ + kk*32 + lq*8];
  __syncthreads();   // Xs reads done everywhere; VT complete

  // ---- mix: head h=w: mix[q,c] = attn_h(64x64) @ vf[:,c] ----
  f32x4 acc2[4][2];
  #pragma unroll
  for (int mt = 0; mt < 4; ++mt)
    #pragma unroll
    for (int nt = 0; nt < 2; ++nt) acc2[mt][nt] = (f32x4){0.f, 0.f, 0.f, 0.f};
  #pragma unroll
  for (int kk = 0; kk < 2; ++kk){
    short8 bfr[2];
    #pragma unroll
    for (int nt = 0; nt < 2; ++nt)
      bfr[nt] = *(const short8*)&VT[(h * 32 + nt * 16 + lm) * VS + kk * 32 + lq * 8];
    #pragma unroll
    for (int mt = 0; mt < 4; ++mt)
      #pragma unroll
      for (int nt = 0; nt < 2; ++nt)
        acc2[mt][nt] = __builtin_amdgcn_mfma_f32_16x16x32_bf16(atf[kk*4+mt], bfr[nt], acc2[mt][nt], 0, 0, 0);
  }
  // ---- prefetch Wp half1 during mix/Ms-write (32 VGPR) ----
  short8 wpf1[8];
  #pragma unroll
  for (int kk = 0; kk < 4; ++kk)
    #pragma unroll
    for (int nt = 0; nt < 2; ++nt)
      wpf1[kk*2+nt] = *(const short8*)&wp[(long)(cw + nt*16 + lm) * D_ + (kk + 4)*32 + lq*8];
  // write mix into Ms (= Xs buffer), row-major
  #pragma unroll
  for (int mt = 0; mt < 4; ++mt)
    #pragma unroll
    for (int nt = 0; nt < 2; ++nt){
      int col = h * 32 + nt * 16 + lm;
      #pragma unroll
      for (int r = 0; r < 4; ++r){
        int row = mt * 16 + lq * 4 + r;
        Xs[row * XS + col] = f2bf(acc2[mt][nt][r]);
      }
    }
  __syncthreads();

  // ---- GEMM3: out = Ms(64x256) @ Wproj^T (weights in registers) ----
  f32x4 acc3[4][2];
  #pragma unroll
  for (int mt = 0; mt < 4; ++mt)
    #pragma unroll
    for (int nt = 0; nt < 2; ++nt) acc3[mt][nt] = (f32x4){0.f, 0.f, 0.f, 0.f};
  #pragma unroll
  for (int kk = 0; kk < 4; ++kk){
    short8 af[4];
    #pragma unroll
    for (int mt = 0; mt < 4; ++mt)
      af[mt] = *(const short8*)&Xs[(mt * 16 + lm) * XS + kk * 32 + lq * 8];
    #pragma unroll
    for (int mt = 0; mt < 4; ++mt)
      #pragma unroll
      for (int nt = 0; nt < 2; ++nt)
        acc3[mt][nt] = __builtin_amdgcn_mfma_f32_16x16x32_bf16(af[mt], wpf0[kk*2+nt], acc3[mt][nt], 0, 0, 0);
  }
  #pragma unroll
  for (int kk = 0; kk < 4; ++kk){
    short8 af[4];
    #pragma unroll
    for (int mt = 0; mt < 4; ++mt)
      af[mt] = *(const short8*)&Xs[(mt * 16 + lm) * XS + (kk + 4) * 32 + lq * 8];
    #pragma unroll
    for (int mt = 0; mt < 4; ++mt)
      #pragma unroll
      for (int nt = 0; nt < 2; ++nt)
        acc3[mt][nt] = __builtin_amdgcn_mfma_f32_16x16x32_bf16(af[mt], wpf1[kk*2+nt], acc3[mt][nt], 0, 0, 0);
  }
  // ---- residual prefetch then epilogue: + b_proj + x, store fp32 ----
  float rx[4][2][4];
  #pragma unroll
  for (int mt = 0; mt < 4; ++mt)
    #pragma unroll
    for (int nt = 0; nt < 2; ++nt){
      int e = cw + nt * 16 + lm;
      #pragma unroll
      for (int r = 0; r < 4; ++r){
        int vr = mt * 16 + lq * 4 + r;
        rx[mt][nt][r] = x[(((long)b * V_ + vr) * T1_ + t) * D_ + e];
      }
    }
  #pragma unroll
  for (int mt = 0; mt < 4; ++mt)
    #pragma unroll
    for (int nt = 0; nt < 2; ++nt){
      int e = cw + nt * 16 + lm;
      #pragma unroll
      for (int r = 0; r < 4; ++r){
        int vr = mt * 16 + lq * 4 + r;
        long g = (((long)b * V_ + vr) * T1_ + t) * D_ + e;
        out[g] = acc3[mt][nt][r] + bp_s[e] + rx[mt][nt][r];
      }
    }
}

// ---------------- launch ----------------
extern "C" void kernel_launch(void* const* d_in, const int* in_sizes, int n_in,
                              void* d_out, int out_size, void* d_ws, size_t ws_size,
                              hipStream_t stream){
  const float* x     = (const float*)d_in[0];
  const int*   mask  = (const int*)d_in[1];
  const float* lnw   = (const float*)d_in[2];
  const float* lnb   = (const float*)d_in[3];
  const float* wqkv  = (const float*)d_in[4];
  const float* wproj = (const float*)d_in[5];
  const float* bproj = (const float*)d_in[6];
  float* out = (float*)d_out;
  char* ws = (char*)d_ws;
  float* musig = (float*)(ws);              // 263168 f
  float* xsum  = (float*)(ws + 1052672);    // 131072 f
  float* qbuf  = (float*)(ws + 1576960);    // 131072 f
  float* kbuf  = (float*)(ws + 2101248);    // 131072 f
  u16*   attn  = (u16*)  (ws + 2625536);    // 262144 u16
  u16*   wv    = (u16*)  (ws + 3149824);    // 65536 u16
  u16*   wp    = (u16*)  (ws + 3280896);    // 65536 u16

  k0_conv<<<512, 256, 0, stream>>>(wqkv, wproj, wv, wp, xsum);
  k1_ln<<<dim3(512, 4), 256, 0, stream>>>(x, mask, lnw, lnb, musig, xsum);
  k2a_qk<<<dim3(512, 4), 256, 0, stream>>>(x, mask, lnw, lnb, wqkv, musig, xsum, qbuf, kbuf);
  k2b_attn<<<64, 256, 0, stream>>>(qbuf, kbuf, attn);
  k3_main<<<B_ * T1_, 512, 0, stream>>>(x, lnw, lnb, bproj, musig, wv, wp, attn, out);
}